// Round 20
// baseline (220.265 us; speedup 1.0000x reference)
//
#include <hip/hip_runtime.h>

// LIF recurrence, T=4, TAU=1.0, THRESH=1.0.
// mem = mem + x[t]; spike = (mem - 1 > 0); mem = spike ? 0 : mem.
//
// v12 (3rd submit — rounds 18-19 were broker timeouts, kernel never ran):
// stream-head reduction. Ledger: MLP depth {1,2,4,8-guaranteed} x
// stream-cleanliness {fragmented, clean} all null; NT loads the only win
// (77->67us). Residual vs the 6.29 TB/s copy (same transaction sizes):
// stream-head count at the DRAM banks. Copy = 2048 blocks x 2 heads = 4K
// heads over ~2K banks -> ~2/bank -> long row-buffer runs. v10 = 2048
// blocks x 8 heads (4 plane-reads + 4 plane-writes) = 16K heads -> ~8/bank
// -> each bank round-robins ~8 rows, activate per handful of transactions.
// Row thrash: invisible to SQ/TCC counters, insensitive to wave-side levers
// (16 rounds of nulls). Fix is pure geometry: block=1024, grid=512 ->
// 512 x 8 = 4K heads (copy's regime), 4x row-run length per head, identical
// coalescing and 16KB-contiguous chunks. Single variable vs v10: geometry.
// Signals: 50-55us kernel => row-thrash confirmed. ~217 bench => declare
// structural ceiling next round (all axes measured).

#define LIF_T 4
#define CHUNKS 4
#define BLOCK 1024

typedef float f32x4 __attribute__((ext_vector_type(4)));

__device__ __forceinline__ f32x4 lif_step(f32x4& mem, f32x4 xt) {
    mem.x += xt.x;
    mem.y += xt.y;
    mem.z += xt.z;
    mem.w += xt.w;
    f32x4 sp;
    sp.x = (mem.x > 1.0f) ? 1.0f : 0.0f;
    sp.y = (mem.y > 1.0f) ? 1.0f : 0.0f;
    sp.z = (mem.z > 1.0f) ? 1.0f : 0.0f;
    sp.w = (mem.w > 1.0f) ? 1.0f : 0.0f;
    mem.x = (sp.x > 0.f) ? 0.f : mem.x;
    mem.y = (sp.y > 0.f) ? 0.f : mem.y;
    mem.z = (sp.z > 0.f) ? 0.f : mem.z;
    mem.w = (sp.w > 0.f) ? 0.f : mem.w;
    return sp;
}

__global__ __launch_bounds__(BLOCK) void
lif_spike_kernel(const float* __restrict__ x, float* __restrict__ out, int n_vec) {
    // Block b owns float4 indices [b*4096, b*4096+4096) of every plane:
    // 4 chunks of 16KB contiguous per plane, walked by 1024 threads.
    const int base = blockIdx.x * (BLOCK * CHUNKS) + threadIdx.x;
    const f32x4* __restrict__ xv = reinterpret_cast<const f32x4*>(x);
    f32x4* __restrict__ ov = reinterpret_cast<f32x4*>(out);

    if (base + (CHUNKS - 1) * BLOCK < n_vec) {
        // ---- fast path (exact cover in the bench shape: 512*4096 == n_vec) ----
        f32x4 mem[CHUNKS];
#pragma unroll
        for (int c = 0; c < CHUNKS; ++c) mem[c] = (f32x4){0.f, 0.f, 0.f, 0.f};

#pragma unroll
        for (int t = 0; t < LIF_T; ++t) {
            const size_t p = (size_t)t * n_vec + base;
            f32x4 xt[CHUNKS];
            // NT loads: full-miss contiguous HBM read stream
#pragma unroll
            for (int c = 0; c < CHUNKS; ++c)
                xt[c] = __builtin_nontemporal_load(&xv[p + c * BLOCK]);
#pragma unroll
            for (int c = 0; c < CHUNKS; ++c) {
                f32x4 sp = lif_step(mem[c], xt[c]);
                // NT store: no cache allocation, decoupled write stream
                __builtin_nontemporal_store(sp, &ov[p + c * BLOCK]);
            }
        }
    } else {
        // ---- tail path (not taken in the exact bench shape) ----
        f32x4 memc[CHUNKS];
#pragma unroll
        for (int c = 0; c < CHUNKS; ++c) memc[c] = (f32x4){0.f, 0.f, 0.f, 0.f};
#pragma unroll
        for (int t = 0; t < LIF_T; ++t) {
#pragma unroll
            for (int c = 0; c < CHUNKS; ++c) {
                int idx = base + c * BLOCK;
                if (idx < n_vec) {
                    f32x4 xt = __builtin_nontemporal_load(&xv[(size_t)t * n_vec + idx]);
                    f32x4 sp = lif_step(memc[c], xt);
                    __builtin_nontemporal_store(sp, &ov[(size_t)t * n_vec + idx]);
                }
            }
        }
    }
}

extern "C" void kernel_launch(void* const* d_in, const int* in_sizes, int n_in,
                              void* d_out, int out_size, void* d_ws, size_t ws_size,
                              hipStream_t stream) {
    const float* x = (const float*)d_in[0];
    float* out = (float*)d_out;

    int n = out_size / LIF_T;      // elements per timestep (8,388,608)
    int n_vec = n / 4;             // float4 groups per timestep (2,097,152)

    const int block = BLOCK;
    int grid = (n_vec + block * CHUNKS - 1) / (block * CHUNKS);  // 512
    lif_spike_kernel<<<grid, block, 0, stream>>>(x, out, n_vec);
}